// Round 8
// baseline (2760.075 us; speedup 1.0000x reference)
//
#include <hip/hip_runtime.h>

typedef unsigned int u32;
typedef unsigned short u16;
typedef __bf16 bf16x8 __attribute__((ext_vector_type(8)));
typedef u16 u16x8 __attribute__((ext_vector_type(8)));
typedef float f32x4 __attribute__((ext_vector_type(4)));
typedef float f32x2 __attribute__((ext_vector_type(2)));

__device__ __forceinline__ u16 f2bf(float f) {
  u32 u = __builtin_bit_cast(u32, f);
  u32 r = (u + 0x7fffu + ((u >> 16) & 1u)) >> 16;   // RTNE
  return (u16)r;
}

// ---------------- fused pre-pass: conv x->xbf | conv x->xq(permuted fp8) | zero | conv W ----------------
// xq word c of row n holds fp8 of feats {c, c+32, c+64, c+96} (bytes 0..3)
__global__ __launch_bounds__(256) void pre_k(const float* __restrict__ x, u16* __restrict__ xbf,
                                             u32* __restrict__ xq,
                                             const float* __restrict__ W, u16* __restrict__ wbf,
                                             u32* __restrict__ bktTotal, int N, int nbkt,
                                             int nbx, int nbz) {
  int b = blockIdx.x, tid = threadIdx.x;
  if (b < nbx) {                       // x -> xbf (natural order bf16)
    int i = b * 256 + tid;             // i-th float4
    if (i < N * 32) {
      const float4 v = *(const float4*)(x + (size_t)i * 4);
      ushort4 o = { f2bf(v.x), f2bf(v.y), f2bf(v.z), f2bf(v.w) };
      *(ushort4*)(xbf + (size_t)i * 4) = o;
    }
  } else if (b < 2 * nbx) {            // x -> xq (permuted fp8)
    int i = (b - nbx) * 256 + tid;     // (row, c)
    if (i < N * 32) {
      int row = i >> 5, c = i & 31;
      const float* xr = x + ((size_t)row << 7) + c;
      float f0 = xr[0], f1 = xr[32], f2 = xr[64], f3 = xr[96];
      u32 p = 0;
      p = __builtin_amdgcn_cvt_pk_fp8_f32(f0, f1, p, false);
      p = __builtin_amdgcn_cvt_pk_fp8_f32(f2, f3, p, true);
      xq[i] = p;
    }
  } else if (b < 2 * nbx + nbz) {      // zero bucket totals
    int i = (b - 2 * nbx) * 256 + tid;
    if (i < nbkt) bktTotal[i] = 0u;
  } else {                             // W (128 x 256 f32) -> bf16
    int i = (b - 2 * nbx - nbz) * 256 + tid;
    if (i < 8192) {
      const float4 v = *(const float4*)(W + (size_t)i * 4);
      ushort4 o = { f2bf(v.x), f2bf(v.y), f2bf(v.z), f2bf(v.w) };
      *(ushort4*)(wbf + (size_t)i * 4) = o;
    }
  }
}

// ---------------- pass A1: per-block LDS histogram over buckets (dst>>7) ----------------
__global__ __launch_bounds__(256) void hist_k(const int* __restrict__ dst, int E,
                                              u32* __restrict__ bktTotal, int nbkt) {
  __shared__ u32 h[1024];
  for (int t = threadIdx.x; t < 1024; t += 256) h[t] = 0u;
  __syncthreads();
  int base = blockIdx.x * 8192;
  for (int it = 0; it < 32; it++) {
    int i = base + it * 256 + threadIdx.x;
    if (i < E) atomicAdd(&h[(u32)dst[i] >> 7], 1u);
  }
  __syncthreads();
  for (int t = threadIdx.x; t < nbkt; t += 256) {
    u32 c = h[t];
    if (c) atomicAdd(&bktTotal[t], c);
  }
}

// ---------------- bucket scan: starts + cursors ----------------
__global__ __launch_bounds__(1024) void bscan_k(const u32* __restrict__ bktTotal, int nbkt,
                                                u32* __restrict__ start, u32* __restrict__ cursor) {
  __shared__ u32 s[1024];
  int t = threadIdx.x;
  u32 v = (t < nbkt) ? bktTotal[t] : 0u;
  s[t] = v;
  __syncthreads();
  for (int off = 1; off < 1024; off <<= 1) {
    u32 x = (t >= off) ? s[t - off] : 0u;
    __syncthreads();
    s[t] += x;
    __syncthreads();
  }
  u32 excl = s[t] - v;
  if (t < nbkt) { start[t] = excl; cursor[t] = excl; }
  if (t == nbkt - 1) start[nbkt] = excl + v;   // == E
}

// ---------------- pass A2: partition edges into bucket regions (packed u32) ----------------
__global__ __launch_bounds__(256) void part_k(const int* __restrict__ src, const int* __restrict__ dst,
                                              int E, u32* __restrict__ cursor,
                                              u32* __restrict__ packed, int nbkt) {
  __shared__ u32 h[1024];
  for (int t = threadIdx.x; t < 1024; t += 256) h[t] = 0u;
  __syncthreads();
  int base = blockIdx.x * 8192;
  for (int it = 0; it < 32; it++) {
    int i = base + it * 256 + threadIdx.x;
    if (i < E) atomicAdd(&h[(u32)dst[i] >> 7], 1u);
  }
  __syncthreads();
  for (int t = threadIdx.x; t < nbkt; t += 256) {
    u32 c = h[t];
    h[t] = c ? atomicAdd(&cursor[t], c) : 0u;   // reserve contiguous per-(block,bucket) range
  }
  __syncthreads();
  for (int it = 0; it < 32; it++) {
    int i = base + it * 256 + threadIdx.x;
    if (i < E) {
      u32 d = (u32)dst[i];
      u32 pos = atomicAdd(&h[d >> 7], 1u);      // LDS atomic
      packed[pos] = (u32)src[i] | ((d & 127u) << 24);
    }
  }
}

// ---------------- fused edge-parallel aggregate + GEMM, one block per 128-node bucket ----------------
// Phase 1: half-wave per edge; lane c adds feats {c,c+32,c+64,c+96} of src row into acc[dst&127].
//          Bank = (4*node + c) mod 32 (row stride 132) -> conflict-free.
// Phase 2: 8 waves x 16-row MFMA strips; A = [xbf rows | LDS means], B = wbf.
#define EDGE_LOAD(J, PK, WV_) { PK = packed[J]; WV_ = xq[((size_t)(PK & 0xFFFFFFu) << 5) + c]; }
#define EDGE_COMMIT(PK, WV_) { u32 ld = (PK) >> 24;                               \
    f32x2 pA = __builtin_amdgcn_cvt_pk_f32_fp8((WV_), false);                     \
    f32x2 pB = __builtin_amdgcn_cvt_pk_f32_fp8((WV_), true);                      \
    atomicAdd(&acc[ld][c], pA.x);      atomicAdd(&acc[ld][c + 32], pA.y);         \
    atomicAdd(&acc[ld][c + 64], pB.x); atomicAdd(&acc[ld][c + 96], pB.y);         \
    if (c == 0) atomicAdd(&cnt[ld], 1u); }

__global__ __launch_bounds__(512, 4) void agg2_k(const u32* __restrict__ packed,
                                                 const u32* __restrict__ start,
                                                 const u32* __restrict__ xq,
                                                 const u16* __restrict__ xbf,
                                                 const u16* __restrict__ wbf,
                                                 const float* __restrict__ bias,
                                                 float* __restrict__ out, int N) {
  __shared__ float acc[128][132];
  __shared__ u32 cnt[128];
  __shared__ float inv[128];
  int b = blockIdx.x, tid = threadIdx.x;
  float* af = &acc[0][0];
  for (int t = tid; t < 128 * 33; t += 512) *(f32x4*)(af + t * 4) = f32x4{0.f, 0.f, 0.f, 0.f};
  if (tid < 128) cnt[tid] = 0u;
  __syncthreads();

  u32 lo = start[b], hi = start[b + 1];
  int wv = tid >> 6, lane = tid & 63;
  int half = lane >> 5, c = lane & 31;

  u32 jj = lo + wv * 2 + half;
  for (; jj + 48 < hi; jj += 64) {
    u32 pk0, pk1, pk2, pk3, w0, w1, w2, w3;
    EDGE_LOAD(jj, pk0, w0)
    EDGE_LOAD(jj + 16, pk1, w1)
    EDGE_LOAD(jj + 32, pk2, w2)
    EDGE_LOAD(jj + 48, pk3, w3)
    EDGE_COMMIT(pk0, w0)
    EDGE_COMMIT(pk1, w1)
    EDGE_COMMIT(pk2, w2)
    EDGE_COMMIT(pk3, w3)
  }
  for (; jj < hi; jj += 16) {
    u32 pk, w;
    EDGE_LOAD(jj, pk, w)
    EDGE_COMMIT(pk, w)
  }
  __syncthreads();
  if (tid < 128) {
    u32 d = cnt[tid];
    inv[tid] = 1.0f / (float)(d ? d : 1u);
  }
  __syncthreads();

  // ---- phase 2: GEMM strips ----
  int la = lane & 15, lb = lane >> 4;
  int rbase = b * 128 + wv * 16;
  int row = wv * 16 + la;
  bf16x8 a[8];
  const u16* ab = xbf + ((size_t)(rbase + la) << 7) + lb * 8;
#pragma unroll
  for (int kb = 0; kb < 4; kb++) a[kb] = *(const bf16x8*)(ab + kb * 32);
  float iv = inv[row];
#pragma unroll
  for (int kb = 0; kb < 4; kb++) {
    const float* mp = &acc[row][kb * 32 + lb * 8];
    float4 m0 = *(const float4*)mp;
    float4 m1 = *(const float4*)(mp + 4);
    u16x8 t;
    t[0] = f2bf(m0.x * iv); t[1] = f2bf(m0.y * iv);
    t[2] = f2bf(m0.z * iv); t[3] = f2bf(m0.w * iv);
    t[4] = f2bf(m1.x * iv); t[5] = f2bf(m1.y * iv);
    t[6] = f2bf(m1.z * iv); t[7] = f2bf(m1.w * iv);
    a[4 + kb] = __builtin_bit_cast(bf16x8, t);
  }

#pragma unroll
  for (int ct = 0; ct < 8; ct++) {
    f32x4 accr = { 0.f, 0.f, 0.f, 0.f };
    const u16* bbase = wbf + ((size_t)(ct * 16 + la) << 8) + lb * 8;
#pragma unroll
    for (int kb = 0; kb < 8; kb++) {
      bf16x8 bv = *(const bf16x8*)(bbase + kb * 32);
      accr = __builtin_amdgcn_mfma_f32_16x16x32_bf16(a[kb], bv, accr, 0, 0, 0);
    }
    float bc = bias[ct * 16 + la];
#pragma unroll
    for (int j = 0; j < 4; j++) {
      int r = rbase + lb * 4 + j;
      if (r < N) out[((size_t)r << 7) + ct * 16 + la] = accr[j] + bc;
    }
  }
}

extern "C" void kernel_launch(void* const* d_in, const int* in_sizes, int n_in,
                              void* d_out, int out_size, void* d_ws, size_t ws_size,
                              hipStream_t stream) {
  const float* x    = (const float*)d_in[0];
  const int*   ei   = (const int*)d_in[1];
  const float* W    = (const float*)d_in[2];
  const float* bias = (const float*)d_in[3];
  const int N = in_sizes[0] / 128;
  const int E = in_sizes[1] / 2;
  const int nbkt = (N + 127) >> 7;           // 128-node buckets (<=1024)
  const int* src = ei;
  const int* dst = ei + E;
  float* out = (float*)d_out;

  // everything lives in ws (d_out is written concurrently by early blocks of agg2_k)
  char* ws = (char*)d_ws;
  u32* packed   = (u32*)ws;                  // E
  size_t off = ((size_t)E * 4 + 255) & ~(size_t)255;
  u32* bktTotal = (u32*)(ws + off);          // nbkt
  u32* start    = bktTotal + nbkt;           // nbkt+1
  u32* cursor   = start + nbkt + 1;          // nbkt
  off += ((size_t)(3 * nbkt + 1) * 4 + 255) & ~(size_t)255;
  u16* xbf = (u16*)(ws + off);               // N*128 bf16
  off += (size_t)N * 128 * 2;
  off = (off + 255) & ~(size_t)255;
  u32* xq = (u32*)(ws + off);                // N*32 u32 (permuted fp8)
  off += (size_t)N * 128;
  off = (off + 255) & ~(size_t)255;
  u16* wbf = (u16*)(ws + off);               // 128*256 bf16

  const int nbx = (N * 32 + 255) / 256;
  const int nbz = (nbkt + 255) / 256;
  const int nba = (E + 8191) / 8192;
  pre_k<<<2 * nbx + nbz + 32, 256, 0, stream>>>(x, xbf, xq, W, wbf, bktTotal, N, nbkt, nbx, nbz);
  hist_k<<<nba, 256, 0, stream>>>(dst, E, bktTotal, nbkt);
  bscan_k<<<1, 1024, 0, stream>>>(bktTotal, nbkt, start, cursor);
  part_k<<<nba, 256, 0, stream>>>(src, dst, E, cursor, packed, nbkt);
  agg2_k<<<nbkt, 512, 0, stream>>>(packed, start, xq, xbf, wbf, bias, out, N);
}

// Round 9
// 232.497 us; speedup vs baseline: 11.8714x; 11.8714x over previous
//
#include <hip/hip_runtime.h>

typedef unsigned int u32;
typedef unsigned short u16;
typedef unsigned char u8;
typedef __bf16 bf16x8 __attribute__((ext_vector_type(8)));
typedef float f32x4 __attribute__((ext_vector_type(4)));
typedef float f32x2 __attribute__((ext_vector_type(2)));

__device__ __forceinline__ u16 f2bf(float f) {
  u32 u = __builtin_bit_cast(u32, f);
  u32 r = (u + 0x7fffu + ((u >> 16) & 1u)) >> 16;   // RTNE
  return (u16)r;
}

// ---------------- fused pre-pass: conv x (bf16 + natural fp8) | zero bktTotal | conv W ----------------
__global__ __launch_bounds__(256) void pre_k(const float* __restrict__ x, u16* __restrict__ xbf,
                                             u32* __restrict__ xq,
                                             const float* __restrict__ W, u16* __restrict__ wbf,
                                             u32* __restrict__ bktTotal, int N, int nbkt,
                                             int nbx, int nbz) {
  int b = blockIdx.x, tid = threadIdx.x;
  if (b < nbx) {                       // x -> xbf (bf16) + xq (fp8 e4m3, natural order, 4/u32)
    int i = b * 256 + tid;             // i-th float4
    if (i < N * 32) {
      const float4 v = *(const float4*)(x + (size_t)i * 4);
      ushort4 o = { f2bf(v.x), f2bf(v.y), f2bf(v.z), f2bf(v.w) };
      *(ushort4*)(xbf + (size_t)i * 4) = o;
      u32 p = 0;
      p = __builtin_amdgcn_cvt_pk_fp8_f32(v.x, v.y, p, false);
      p = __builtin_amdgcn_cvt_pk_fp8_f32(v.z, v.w, p, true);
      xq[i] = p;
    }
  } else if (b < nbx + nbz) {          // zero bucket totals
    int i = (b - nbx) * 256 + tid;
    if (i < nbkt) bktTotal[i] = 0u;
  } else {                             // W (128 x 256 f32) -> bf16
    int i = (b - nbx - nbz) * 256 + tid;
    if (i < 8192) {
      const float4 v = *(const float4*)(W + (size_t)i * 4);
      ushort4 o = { f2bf(v.x), f2bf(v.y), f2bf(v.z), f2bf(v.w) };
      *(ushort4*)(wbf + (size_t)i * 4) = o;
    }
  }
}

// ---------------- pass A1: per-block LDS histogram over buckets (dst>>8) ----------------
__global__ __launch_bounds__(256) void hist_k(const int* __restrict__ dst, int E,
                                              u32* __restrict__ bktTotal, int nbkt) {
  __shared__ u32 h[512];
  for (int t = threadIdx.x; t < 512; t += 256) h[t] = 0u;
  __syncthreads();
  int base = blockIdx.x * 8192;
  for (int it = 0; it < 32; it++) {
    int i = base + it * 256 + threadIdx.x;
    if (i < E) atomicAdd(&h[(u32)dst[i] >> 8], 1u);
  }
  __syncthreads();
  for (int t = threadIdx.x; t < nbkt; t += 256) {
    u32 c = h[t];
    if (c) atomicAdd(&bktTotal[t], c);
  }
}

// ---------------- bucket scan: starts, cursors, offsets[N] ----------------
__global__ __launch_bounds__(512) void bscan_k(const u32* __restrict__ bktTotal, int nbkt,
                                               int E, int N, u32* __restrict__ start,
                                               u32* __restrict__ cursor, u32* __restrict__ offsets) {
  __shared__ u32 s[512];
  int t = threadIdx.x;
  u32 v = (t < nbkt) ? bktTotal[t] : 0u;
  s[t] = v;
  __syncthreads();
  for (int off = 1; off < 512; off <<= 1) {
    u32 x = (t >= off) ? s[t - off] : 0u;
    __syncthreads();
    s[t] += x;
    __syncthreads();
  }
  u32 excl = s[t] - v;
  if (t < nbkt) { start[t] = excl; cursor[t] = excl; }
  if (t == nbkt - 1) start[nbkt] = excl + v;   // == E
  if (t == 0) offsets[N] = (u32)E;
}

// ---------------- pass A2: partition edges into bucket regions (packed u32) ----------------
__global__ __launch_bounds__(256) void part_k(const int* __restrict__ src, const int* __restrict__ dst,
                                              int E, u32* __restrict__ cursor,
                                              u32* __restrict__ packed, int nbkt) {
  __shared__ u32 h[512];
  for (int t = threadIdx.x; t < 512; t += 256) h[t] = 0u;
  __syncthreads();
  int base = blockIdx.x * 8192;
  for (int it = 0; it < 32; it++) {
    int i = base + it * 256 + threadIdx.x;
    if (i < E) atomicAdd(&h[(u32)dst[i] >> 8], 1u);
  }
  __syncthreads();
  for (int t = threadIdx.x; t < nbkt; t += 256) {
    u32 c = h[t];
    h[t] = c ? atomicAdd(&cursor[t], c) : 0u;   // reserve contiguous per-(block,bucket) range
  }
  __syncthreads();
  for (int it = 0; it < 32; it++) {
    int i = base + it * 256 + threadIdx.x;
    if (i < E) {
      u32 d = (u32)dst[i];
      u32 pos = atomicAdd(&h[d >> 8], 1u);      // LDS atomic (u32 - fast path)
      packed[pos] = (u32)src[i] | ((d & 255u) << 24);
    }
  }
}

// ---------------- pass B: per-bucket counting sort -> offsets + ssrc ----------------
__global__ __launch_bounds__(256) void bucket_k(const u32* __restrict__ packed,
                                                const u32* __restrict__ start, int N,
                                                u32* __restrict__ offsets, int* __restrict__ ssrc) {
  __shared__ u32 cnt[256];
  __shared__ u32 scn[256];
  __shared__ u32 cur[256];
  int b = blockIdx.x, t = threadIdx.x;
  u32 lo = start[b], hi = start[b + 1];
  cnt[t] = 0u;
  __syncthreads();
  for (u32 j = lo + t; j < hi; j += 256) atomicAdd(&cnt[packed[j] >> 24], 1u);
  __syncthreads();
  u32 v = cnt[t];
  scn[t] = v;
  __syncthreads();
  for (int off = 1; off < 256; off <<= 1) {
    u32 x = (t >= off) ? scn[t - off] : 0u;
    __syncthreads();
    scn[t] += x;
    __syncthreads();
  }
  u32 base = lo + scn[t] - v;     // exclusive position of this node's segment
  int node = b * 256 + t;
  if (node < N) offsets[node] = base;
  cur[t] = base;
  __syncthreads();
  for (u32 j = lo + t; j < hi; j += 256) {
    u32 w = packed[j];
    u32 pos = atomicAdd(&cur[w >> 24], 1u);   // LDS atomic (u32)
    ssrc[pos] = (int)(w & 0xFFFFFFu);
  }
}

// ---------------- fused staged-gather aggregate + GEMM ----------------
// Block = 128 nodes, 8 waves. 32 chunks/block: chunk c stages edges j = lo+c+32k (k=slot)
// into LDS (fp8 rows) with uniform straight-line loads; reduce phase reads LDS (cheap
// divergence). Pipeline: rows for c+1 and idx for c+2 are issued BEFORE chunk c's
// ds_write + raw barrier, so vmem stays in flight across barriers (counted waits).
#define SROWB 160      // staged row stride (128B data + 32B pad -> bank spread)
#define MAXSLOT 160
#define MSTR 144       // means LDS stride in u16 (288B, 16B-aligned)

#define DECW(W, J) { f32x2 pl = __builtin_amdgcn_cvt_pk_f32_fp8((W), false); \
                     f32x2 ph = __builtin_amdgcn_cvt_pk_f32_fp8((W), true);  \
                     acc2[J] += pl; acc2[(J) + 1] += ph; }

__global__ __launch_bounds__(512, 2) void agg3_k(const int* __restrict__ ssrc,
                                                 const u32* __restrict__ offsets,
                                                 const u32* __restrict__ xq,
                                                 const u16* __restrict__ xbf,
                                                 const u16* __restrict__ wbf,
                                                 const float* __restrict__ bias,
                                                 float* __restrict__ out, int N) {
  __shared__ u8 stage[MAXSLOT * SROWB];     // 25600 B
  __shared__ u16 mlds[128 * MSTR];          // 36864 B
  const int tid = threadIdx.x;
  const int wv = tid >> 6, lane = tid & 63;
  const int b = blockIdx.x;
  const int base = b * 128;
  const u32 lo = offsets[base];
  const int nend = min(base + 128, N);
  const u32 hi = offsets[nend];
  const u32 nE = hi - lo;
  const u32 hm1 = hi - 1u;                  // if hi==0 this wraps; min() then keeps j (safe, j<E)

  const int nodeL = tid >> 2, q = tid & 3;
  const int nodeG = base + nodeL;
  u32 s0 = lo, s1 = lo;
  if (nodeG < N) { s0 = offsets[nodeG]; s1 = offsets[nodeG + 1]; }

  f32x2 acc2[16];
#pragma unroll
  for (int i = 0; i < 16; i++) acc2[i] = f32x2{0.f, 0.f};

  const int lgrp = lane >> 3;               // edge-within-inst (0..7)
  const int lseg = lane & 7;                // 16B slice of the 128B row
  const int sb0 = wv * 20;                  // wave's slot region (20 active, 24 covered)
  const int sl0 = sb0 + lgrp, sl1 = sb0 + 8 + lgrp, sl2 = sb0 + 16 + lgrp;
  const char* xqb = (const char*)xq;

#define IDXLOAD(C, I0, I1, I2) { \
    u32 j0 = lo + (u32)(C) + (u32)sl0 * 32u; \
    u32 j1 = lo + (u32)(C) + (u32)sl1 * 32u; \
    u32 j2 = lo + (u32)(C) + (u32)sl2 * 32u; \
    I0 = (u32)ssrc[min(j0, hm1)]; \
    I1 = (u32)ssrc[min(j1, hm1)]; \
    I2 = (u32)ssrc[min(j2, hm1)]; }

#define ROWLOAD(R0, R1, R2, I0, I1, I2) { \
    R0 = *(const uint4*)(xqb + ((size_t)(I0) << 7) + (lseg << 4)); \
    R1 = *(const uint4*)(xqb + ((size_t)(I1) << 7) + (lseg << 4)); \
    R2 = *(const uint4*)(xqb + ((size_t)(I2) << 7) + (lseg << 4)); }

#define DSWRITE(R0, R1, R2) { \
    if (sl0 < MAXSLOT) *(uint4*)(stage + sl0 * SROWB + (lseg << 4)) = R0; \
    if (sl1 < MAXSLOT) *(uint4*)(stage + sl1 * SROWB + (lseg << 4)) = R1; \
    if (sl2 < MAXSLOT) *(uint4*)(stage + sl2 * SROWB + (lseg << 4)) = R2; }

#define REDUCE(C) { \
    int d0 = (int)(s0 - lo) - (C); int k0 = (d0 + 31) >> 5; \
    int d1 = (int)(s1 - lo) - (C); int k1 = (d1 + 31) >> 5; \
    int kc = ((int)nE - (C) + 31) >> 5; \
    if (kc > MAXSLOT) kc = MAXSLOT; \
    if (k1 > kc) k1 = kc; \
    for (int k = k0; k < k1; k++) { \
      const uint4* pp = (const uint4*)(stage + k * SROWB + (q << 5)); \
      uint4 w0 = pp[0]; uint4 w1 = pp[1]; \
      DECW(w0.x, 0) DECW(w0.y, 2) DECW(w0.z, 4) DECW(w0.w, 6) \
      DECW(w1.x, 8) DECW(w1.y, 10) DECW(w1.z, 12) DECW(w1.w, 14) \
    } }

  uint4 rA0, rA1, rA2, rB0, rB1, rB2;
  u32 iA0, iA1, iA2, iB0, iB1, iB2;
  u32 t0, t1, t2;

  // prologue: rows chunk 0, idx chunk 1
  IDXLOAD(0, t0, t1, t2)
  ROWLOAD(rA0, rA1, rA2, t0, t1, t2)
  IDXLOAD(1, iA0, iA1, iA2)

  for (int c = 0; c < 32; c += 2) {
    // ---- chunk c (rows in rA*, idx for c+1 in iA*) ----
    IDXLOAD(min(c + 2, 31), iB0, iB1, iB2)
    ROWLOAD(rB0, rB1, rB2, iA0, iA1, iA2)       // rows chunk c+1 (idx ready ~1 chunk ago)
    DSWRITE(rA0, rA1, rA2)                      // compiler emits counted vmcnt for rA deps
    asm volatile("s_waitcnt lgkmcnt(0)" ::: "memory");
    __builtin_amdgcn_s_barrier();
    REDUCE(c)
    asm volatile("" ::: "memory");
    __builtin_amdgcn_s_barrier();
    asm volatile("" ::: "memory");
    // ---- chunk c+1 (rows in rB*, idx for c+2 in iB*) ----
    IDXLOAD(min(c + 3, 31), iA0, iA1, iA2)
    ROWLOAD(rA0, rA1, rA2, iB0, iB1, iB2)       // rows chunk c+2
    DSWRITE(rB0, rB1, rB2)
    asm volatile("s_waitcnt lgkmcnt(0)" ::: "memory");
    __builtin_amdgcn_s_barrier();
    REDUCE(c + 1)
    asm volatile("" ::: "memory");
    __builtin_amdgcn_s_barrier();
    asm volatile("" ::: "memory");
  }

  // ---- means -> LDS ----
  {
    u32 deg = s1 - s0;
    float iv = 1.0f / (float)(deg ? deg : 1u);
    u32 w[16];
#pragma unroll
    for (int i = 0; i < 16; i++)
      w[i] = (u32)f2bf(acc2[i].x * iv) | ((u32)f2bf(acc2[i].y * iv) << 16);
    u32* mp = (u32*)(mlds + nodeL * MSTR + q * 32);
    *(uint4*)(mp + 0)  = uint4{w[0], w[1], w[2], w[3]};
    *(uint4*)(mp + 4)  = uint4{w[4], w[5], w[6], w[7]};
    *(uint4*)(mp + 8)  = uint4{w[8], w[9], w[10], w[11]};
    *(uint4*)(mp + 12) = uint4{w[12], w[13], w[14], w[15]};
  }
  __syncthreads();

  // ---- GEMM: 8 waves x 16-row strips; A = [xbf rows | LDS means], B = wbf ----
  {
    int la = lane & 15, lb = lane >> 4;
    int rbase = base + wv * 16;
    bf16x8 a[8];
    const u16* ab = xbf + ((size_t)(rbase + la) << 7) + lb * 8;
#pragma unroll
    for (int kb = 0; kb < 4; kb++) a[kb] = *(const bf16x8*)(ab + kb * 32);
#pragma unroll
    for (int kb = 0; kb < 4; kb++)
      a[4 + kb] = *(const bf16x8*)(mlds + (wv * 16 + la) * MSTR + kb * 32 + lb * 8);

#pragma unroll
    for (int ct = 0; ct < 8; ct++) {
      f32x4 accr = { 0.f, 0.f, 0.f, 0.f };
      const u16* bbase = wbf + ((size_t)(ct * 16 + la) << 8) + lb * 8;
#pragma unroll
      for (int kb = 0; kb < 8; kb++) {
        bf16x8 bv = *(const bf16x8*)(bbase + kb * 32);
        accr = __builtin_amdgcn_mfma_f32_16x16x32_bf16(a[kb], bv, accr, 0, 0, 0);
      }
      float bc = bias[ct * 16 + la];
#pragma unroll
      for (int j = 0; j < 4; j++) {
        int r = rbase + lb * 4 + j;
        if (r < N) out[((size_t)r << 7) + ct * 16 + la] = accr[j] + bc;
      }
    }
  }
}

extern "C" void kernel_launch(void* const* d_in, const int* in_sizes, int n_in,
                              void* d_out, int out_size, void* d_ws, size_t ws_size,
                              hipStream_t stream) {
  const float* x    = (const float*)d_in[0];
  const int*   ei   = (const int*)d_in[1];
  const float* W    = (const float*)d_in[2];
  const float* bias = (const float*)d_in[3];
  const int N = in_sizes[0] / 128;
  const int E = in_sizes[1] / 2;
  const int nbkt = (N + 255) >> 8;           // 256-node buckets for the sort
  const int* src = ei;
  const int* dst = ei + E;
  float* out = (float*)d_out;

  // transient CSR-build scratch in d_out (dead before agg3_k writes out):
  u32* packed   = (u32*)d_out;               // E
  u32* bktTotal = packed + E;                // nbkt
  u32* start    = bktTotal + nbkt;           // nbkt+1
  u32* cursor   = start + nbkt + 1;          // nbkt

  char* ws = (char*)d_ws;
  u32* offsets = (u32*)ws;                   // N+1
  size_t off = ((size_t)(N + 1) * 4 + 255) & ~(size_t)255;
  int* ssrc = (int*)(ws + off);              // E
  off += (size_t)E * 4;
  off = (off + 255) & ~(size_t)255;
  u16* xbf = (u16*)(ws + off);               // N*128 bf16
  off += (size_t)N * 128 * 2;
  off = (off + 255) & ~(size_t)255;
  u32* xq = (u32*)(ws + off);                // N*32 u32 (natural-order fp8)
  off += (size_t)N * 128;
  off = (off + 255) & ~(size_t)255;
  u16* wbf = (u16*)(ws + off);               // 128*256 bf16

  const int nbx = (N * 32 + 255) / 256;
  const int nbz = (nbkt + 255) / 256;
  const int nba = (E + 8191) / 8192;
  pre_k<<<nbx + nbz + 32, 256, 0, stream>>>(x, xbf, xq, W, wbf, bktTotal, N, nbkt, nbx, nbz);
  hist_k<<<nba, 256, 0, stream>>>(dst, E, bktTotal, nbkt);
  bscan_k<<<1, 512, 0, stream>>>(bktTotal, nbkt, E, N, start, cursor, offsets);
  part_k<<<nba, 256, 0, stream>>>(src, dst, E, cursor, packed, nbkt);
  bucket_k<<<nbkt, 256, 0, stream>>>(packed, start, N, offsets, ssrc);
  agg3_k<<<(N + 127) / 128, 512, 0, stream>>>(ssrc, offsets, xq, xbf, wbf, bias, out, N);
}

// Round 10
// 230.828 us; speedup vs baseline: 11.9573x; 1.0072x over previous
//
#include <hip/hip_runtime.h>

typedef unsigned int u32;
typedef unsigned short u16;
typedef __bf16 bf16x8 __attribute__((ext_vector_type(8)));
typedef float f32x4 __attribute__((ext_vector_type(4)));
typedef float f32x2 __attribute__((ext_vector_type(2)));

__device__ __forceinline__ u16 f2bf(float f) {
  u32 u = __builtin_bit_cast(u32, f);
  u32 r = (u + 0x7fffu + ((u >> 16) & 1u)) >> 16;   // RTNE
  return (u16)r;
}

// ---------------- fused pre-pass: conv x (bf16 + fp8) | zero bktTotal | conv W ----------------
__global__ __launch_bounds__(256) void pre_k(const float* __restrict__ x, u16* __restrict__ xbf,
                                             u32* __restrict__ xq,
                                             const float* __restrict__ W, u16* __restrict__ wbf,
                                             u32* __restrict__ bktTotal, int N, int nbkt,
                                             int nbx, int nbz) {
  int b = blockIdx.x, tid = threadIdx.x;
  if (b < nbx) {                       // x -> xbf (bf16) + xq (fp8 e4m3, natural order, 4/u32)
    int i = b * 256 + tid;             // i-th float4
    if (i < N * 32) {
      const float4 v = *(const float4*)(x + (size_t)i * 4);
      ushort4 o = { f2bf(v.x), f2bf(v.y), f2bf(v.z), f2bf(v.w) };
      *(ushort4*)(xbf + (size_t)i * 4) = o;
      u32 p = 0;
      p = __builtin_amdgcn_cvt_pk_fp8_f32(v.x, v.y, p, false);
      p = __builtin_amdgcn_cvt_pk_fp8_f32(v.z, v.w, p, true);
      xq[i] = p;
    }
  } else if (b < nbx + nbz) {          // zero bucket totals
    int i = (b - nbx) * 256 + tid;
    if (i < nbkt) bktTotal[i] = 0u;
  } else {                             // W (128 x 256 f32) -> bf16
    int i = (b - nbx - nbz) * 256 + tid;
    if (i < 8192) {
      const float4 v = *(const float4*)(W + (size_t)i * 4);
      ushort4 o = { f2bf(v.x), f2bf(v.y), f2bf(v.z), f2bf(v.w) };
      *(ushort4*)(wbf + (size_t)i * 4) = o;
    }
  }
}

// ---------------- pass A1: per-block LDS histogram over buckets (dst>>8) ----------------
__global__ __launch_bounds__(256) void hist_k(const int* __restrict__ dst, int E,
                                              u32* __restrict__ bktTotal, int nbkt) {
  __shared__ u32 h[512];
  for (int t = threadIdx.x; t < 512; t += 256) h[t] = 0u;
  __syncthreads();
  int base = blockIdx.x * 8192;
  for (int it = 0; it < 32; it++) {
    int i = base + it * 256 + threadIdx.x;
    if (i < E) atomicAdd(&h[(u32)dst[i] >> 8], 1u);
  }
  __syncthreads();
  for (int t = threadIdx.x; t < nbkt; t += 256) {
    u32 c = h[t];
    if (c) atomicAdd(&bktTotal[t], c);
  }
}

// ---------------- bucket scan: starts, cursors, offsets[N] ----------------
__global__ __launch_bounds__(512) void bscan_k(const u32* __restrict__ bktTotal, int nbkt,
                                               int E, int N, u32* __restrict__ start,
                                               u32* __restrict__ cursor, u32* __restrict__ offsets) {
  __shared__ u32 s[512];
  int t = threadIdx.x;
  u32 v = (t < nbkt) ? bktTotal[t] : 0u;
  s[t] = v;
  __syncthreads();
  for (int off = 1; off < 512; off <<= 1) {
    u32 x = (t >= off) ? s[t - off] : 0u;
    __syncthreads();
    s[t] += x;
    __syncthreads();
  }
  u32 excl = s[t] - v;
  if (t < nbkt) { start[t] = excl; cursor[t] = excl; }
  if (t == nbkt - 1) start[nbkt] = excl + v;   // == E
  if (t == 0) offsets[N] = (u32)E;
}

// ---------------- pass A2: partition edges into bucket regions (packed u32) ----------------
__global__ __launch_bounds__(256) void part_k(const int* __restrict__ src, const int* __restrict__ dst,
                                              int E, u32* __restrict__ cursor,
                                              u32* __restrict__ packed, int nbkt) {
  __shared__ u32 h[512];
  for (int t = threadIdx.x; t < 512; t += 256) h[t] = 0u;
  __syncthreads();
  int base = blockIdx.x * 8192;
  for (int it = 0; it < 32; it++) {
    int i = base + it * 256 + threadIdx.x;
    if (i < E) atomicAdd(&h[(u32)dst[i] >> 8], 1u);
  }
  __syncthreads();
  for (int t = threadIdx.x; t < nbkt; t += 256) {
    u32 c = h[t];
    h[t] = c ? atomicAdd(&cursor[t], c) : 0u;   // reserve contiguous per-(block,bucket) range
  }
  __syncthreads();
  for (int it = 0; it < 32; it++) {
    int i = base + it * 256 + threadIdx.x;
    if (i < E) {
      u32 d = (u32)dst[i];
      u32 pos = atomicAdd(&h[d >> 8], 1u);      // LDS atomic (u32 - fast path)
      packed[pos] = (u32)src[i] | ((d & 255u) << 24);
    }
  }
}

// ---------------- pass B: per-bucket counting sort -> offsets + ssrc ----------------
__global__ __launch_bounds__(256) void bucket_k(const u32* __restrict__ packed,
                                                const u32* __restrict__ start, int N,
                                                u32* __restrict__ offsets, int* __restrict__ ssrc) {
  __shared__ u32 cnt[256];
  __shared__ u32 scn[256];
  __shared__ u32 cur[256];
  int b = blockIdx.x, t = threadIdx.x;
  u32 lo = start[b], hi = start[b + 1];
  cnt[t] = 0u;
  __syncthreads();
  for (u32 j = lo + t; j < hi; j += 256) atomicAdd(&cnt[packed[j] >> 24], 1u);
  __syncthreads();
  u32 v = cnt[t];
  scn[t] = v;
  __syncthreads();
  for (int off = 1; off < 256; off <<= 1) {
    u32 x = (t >= off) ? scn[t - off] : 0u;
    __syncthreads();
    scn[t] += x;
    __syncthreads();
  }
  u32 base = lo + scn[t] - v;     // exclusive position of this node's segment
  int node = b * 256 + t;
  if (node < N) offsets[node] = base;
  cur[t] = base;
  __syncthreads();
  for (u32 j = lo + t; j < hi; j += 256) {
    u32 w = packed[j];
    u32 pos = atomicAdd(&cur[w >> 24], 1u);   // LDS atomic (u32)
    ssrc[pos] = (int)(w & 0xFFFFFFu);
  }
}

// ---------------- fused aggregate + GEMM, 8 waves / 64 nodes per block ----------------
// Phase 1: each 16-lane sub-group owns one node; wave handles 8 nodes (2 rounds of 4
// concurrent); uint4 index loads + 8 fp8 rows in flight per sub-group.
// Phase 2: wave-pairs: 4 strips x 2 column-halves (4 MFMA col-tiles each).
#define DEC8(vv) { f32x2 p;                                             \
    p = __builtin_amdgcn_cvt_pk_f32_fp8((vv).x, false); a0 += p.x; a1 += p.y; \
    p = __builtin_amdgcn_cvt_pk_f32_fp8((vv).x, true);  a2 += p.x; a3 += p.y; \
    p = __builtin_amdgcn_cvt_pk_f32_fp8((vv).y, false); a4 += p.x; a5 += p.y; \
    p = __builtin_amdgcn_cvt_pk_f32_fp8((vv).y, true);  a6 += p.x; a7 += p.y; }

__global__ __launch_bounds__(512) void fuse_k(const int* __restrict__ ssrc,
                                              const u32* __restrict__ offsets,
                                              const u32* __restrict__ xq,
                                              const u16* __restrict__ xbf,
                                              const u16* __restrict__ wbf,
                                              const float* __restrict__ bias,
                                              float* __restrict__ out, int N) {
  __shared__ u16 mlds[64][136];               // padded stride vs bank conflicts
  int wv = threadIdx.x >> 6, lane = threadIdx.x & 63;
  int sub = lane >> 4, cl = lane & 15;
  int wbase = blockIdx.x * 64;

  // ---- phase 1: 2 rounds x 4 concurrent nodes per wave (8 nodes/wave) ----
  for (int r = 0; r < 2; r++) {
    int ln = wv * 8 + r * 4 + sub;            // local node in block [0,64)
    int node = wbase + ln;
    float a0=0.f,a1=0.f,a2=0.f,a3=0.f,a4=0.f,a5=0.f,a6=0.f,a7=0.f;
    u32 deg = 0;
    if (node < N) {
      u32 s0 = offsets[node], s1 = offsets[node + 1];
      deg = s1 - s0;
      u32 j = s0;
      for (; j + 7 < s1; j += 8) {            // 8 rows in flight
        uint4 iA = *(const uint4*)(ssrc + j);
        uint4 iB = *(const uint4*)(ssrc + j + 4);
        uint2 v0 = *(const uint2*)(xq + ((size_t)iA.x << 5) + (cl << 1));
        uint2 v1 = *(const uint2*)(xq + ((size_t)iA.y << 5) + (cl << 1));
        uint2 v2 = *(const uint2*)(xq + ((size_t)iA.z << 5) + (cl << 1));
        uint2 v3 = *(const uint2*)(xq + ((size_t)iA.w << 5) + (cl << 1));
        uint2 v4 = *(const uint2*)(xq + ((size_t)iB.x << 5) + (cl << 1));
        uint2 v5 = *(const uint2*)(xq + ((size_t)iB.y << 5) + (cl << 1));
        uint2 v6 = *(const uint2*)(xq + ((size_t)iB.z << 5) + (cl << 1));
        uint2 v7 = *(const uint2*)(xq + ((size_t)iB.w << 5) + (cl << 1));
        DEC8(v0) DEC8(v1) DEC8(v2) DEC8(v3)
        DEC8(v4) DEC8(v5) DEC8(v6) DEC8(v7)
      }
      for (; j + 3 < s1; j += 4) {
        uint4 iA = *(const uint4*)(ssrc + j);
        uint2 v0 = *(const uint2*)(xq + ((size_t)iA.x << 5) + (cl << 1));
        uint2 v1 = *(const uint2*)(xq + ((size_t)iA.y << 5) + (cl << 1));
        uint2 v2 = *(const uint2*)(xq + ((size_t)iA.z << 5) + (cl << 1));
        uint2 v3 = *(const uint2*)(xq + ((size_t)iA.w << 5) + (cl << 1));
        DEC8(v0) DEC8(v1) DEC8(v2) DEC8(v3)
      }
      for (; j < s1; j++) {
        int e = ssrc[j];
        uint2 v = *(const uint2*)(xq + ((size_t)e << 5) + (cl << 1));
        DEC8(v)
      }
    }
    float inv = 1.0f / (float)(deg ? deg : 1u);
    uint4 o;
    o.x = (u32)f2bf(a0 * inv) | ((u32)f2bf(a1 * inv) << 16);
    o.y = (u32)f2bf(a2 * inv) | ((u32)f2bf(a3 * inv) << 16);
    o.z = (u32)f2bf(a4 * inv) | ((u32)f2bf(a5 * inv) << 16);
    o.w = (u32)f2bf(a6 * inv) | ((u32)f2bf(a7 * inv) << 16);
    *(uint4*)&mlds[ln][cl * 8] = o;           // 16 lanes cover all 128 feats
  }
  __syncthreads();

  // ---- phase 2: 4 strips x 2 col-halves; wave = (strip, half) ----
  int la = cl, lb = sub;
  int strip = wv & 3, ch = wv >> 2;
  int rbase = wbase + strip * 16;
  bf16x8 a[8];
  const u16* ab = xbf + ((size_t)(rbase + la) << 7) + lb * 8;
#pragma unroll
  for (int kb = 0; kb < 4; kb++) a[kb] = *(const bf16x8*)(ab + kb * 32);
#pragma unroll
  for (int kb = 0; kb < 4; kb++) a[4 + kb] = *(const bf16x8*)(&mlds[strip * 16 + la][kb * 32 + lb * 8]);

#pragma unroll
  for (int c = 0; c < 4; c++) {
    int ct = ch * 4 + c;
    f32x4 acc = { 0.f, 0.f, 0.f, 0.f };
    const u16* bbase = wbf + ((size_t)(ct * 16 + la) << 8) + lb * 8;
#pragma unroll
    for (int kb = 0; kb < 8; kb++) {
      bf16x8 b = *(const bf16x8*)(bbase + kb * 32);
      acc = __builtin_amdgcn_mfma_f32_16x16x32_bf16(a[kb], b, acc, 0, 0, 0);
    }
    float bc = bias[ct * 16 + la];
#pragma unroll
    for (int j = 0; j < 4; j++) {
      int r = rbase + lb * 4 + j;
      if (r < N) out[((size_t)r << 7) + ct * 16 + la] = acc[j] + bc;
    }
  }
}

extern "C" void kernel_launch(void* const* d_in, const int* in_sizes, int n_in,
                              void* d_out, int out_size, void* d_ws, size_t ws_size,
                              hipStream_t stream) {
  const float* x    = (const float*)d_in[0];
  const int*   ei   = (const int*)d_in[1];
  const float* W    = (const float*)d_in[2];
  const float* bias = (const float*)d_in[3];
  const int N = in_sizes[0] / 128;
  const int E = in_sizes[1] / 2;
  const int nbkt = (N + 255) >> 8;           // 256-node buckets
  const int* src = ei;
  const int* dst = ei + E;
  float* out = (float*)d_out;

  // transient CSR-build scratch in d_out (dead before fuse_k writes out):
  u32* packed   = (u32*)d_out;               // E
  u32* bktTotal = packed + E;                // nbkt
  u32* start    = bktTotal + nbkt;           // nbkt+1
  u32* cursor   = start + nbkt + 1;          // nbkt

  char* ws = (char*)d_ws;
  u32* offsets = (u32*)ws;                   // N+1
  size_t off = ((size_t)(N + 1) * 4 + 255) & ~(size_t)255;
  int* ssrc = (int*)(ws + off);              // E
  off += (size_t)E * 4;
  off = (off + 255) & ~(size_t)255;
  u16* xbf = (u16*)(ws + off);               // N*128 bf16
  off += (size_t)N * 128 * 2;
  off = (off + 255) & ~(size_t)255;
  u32* xq = (u32*)(ws + off);                // N*32 u32 (natural-order fp8)
  off += (size_t)N * 128;
  off = (off + 255) & ~(size_t)255;
  u16* wbf = (u16*)(ws + off);               // 128*256 bf16

  const int nbx = (N * 32 + 255) / 256;
  const int nbz = (nbkt + 255) / 256;
  const int nba = (E + 8191) / 8192;
  pre_k<<<nbx + nbz + 32, 256, 0, stream>>>(x, xbf, xq, W, wbf, bktTotal, N, nbkt, nbx, nbz);
  hist_k<<<nba, 256, 0, stream>>>(dst, E, bktTotal, nbkt);
  bscan_k<<<1, 512, 0, stream>>>(bktTotal, nbkt, E, N, start, cursor, offsets);
  part_k<<<nba, 256, 0, stream>>>(src, dst, E, cursor, packed, nbkt);
  bucket_k<<<nbkt, 256, 0, stream>>>(packed, start, N, offsets, ssrc);
  fuse_k<<<(N + 63) / 64, 512, 0, stream>>>(ssrc, offsets, xq, xbf, wbf, bias, out, N);
}